// Round 16
// baseline (86.614 us; speedup 1.0000x reference)
//
#include <hip/hip_runtime.h>
#include <math.h>

// Problem constants: gts/preds [4, 8192, 3] fp32; out [4] fp32.
#define BB 4
#define NPTS 8192
#define THREADS 256
#define SLICES 4                       // ref slices iterated IN-kernel
#define RPS (NPTS / SLICES)            // 2048 refs per slice; 32 KB LDS
#define QPW 32                         // queries per wave
#define QPB (4 * QPW)                  // 128 queries per block
#define QGROUPS (NPTS / QPB)           // 64 query groups per (dir,b)
#define NBLK (2 * BB * QGROUPS)        // 512 blocks

typedef __attribute__((ext_vector_type(8)))  short bf16x8;   // MFMA A/B frag
typedef __attribute__((ext_vector_type(16))) float f32x16;   // MFMA C/D frag

// ws layout: partial[NBLK] floats (2 KB) only.
// MFMA dot = -2 q.r + rr + qq = |q-r|^2 on bf16-rounded points:
//   ref  (A) slots [  x,  y,  z, rr_hi, rr_lo, 1, 1, 0]
//   query(B) slots [-2x,-2y,-2z, 1, 1, qq_hi, qq_lo, 0]
// Role-swapped (R13): A = refs (rows, LDS), B = queries (cols, persistent);
// B's K slots 8-15 zero -> A lanes 32-63 don't-care -> unconditional
// full-wave LDS reads; each lane's D regs = 16 ref-rows for ITS query col
// -> register-local min. R15 SW pipeline kept. R16: single fused kernel —
// pack-on-stage from raw fp32, all slices per block, in-kernel sqrt+sum.

__device__ __forceinline__ unsigned short f2bf(float f) {   // RNE f32->bf16
    unsigned u = __float_as_uint(f);
    u += 0x7FFF + ((u >> 16) & 1);
    return (unsigned short)(u >> 16);
}
__device__ __forceinline__ float bf2f(unsigned short h) {
    return __uint_as_float(((unsigned)h) << 16);
}

__device__ __forceinline__ uint4 make_rfrag(float x, float y, float z) {
    unsigned short hx = f2bf(x), hy = f2bf(y), hz = f2bf(z);
    float fx = bf2f(hx), fy = bf2f(hy), fz = bf2f(hz);
    float rr = fmaf(fx, fx, fmaf(fy, fy, fz * fz));   // fp32 of ROUNDED coords
    unsigned short hh = f2bf(rr);
    unsigned short hl = f2bf(rr - bf2f(hh));
    uint4 v;
    v.x = (unsigned)hx | ((unsigned)hy << 16);
    v.y = (unsigned)hz | ((unsigned)hh << 16);
    v.z = (unsigned)hl | (0x3F80u << 16);
    v.w = 0x3F80u;
    return v;
}

__device__ __forceinline__ bf16x8 make_qfrag(const float* __restrict__ p) {
    unsigned short hx = f2bf(p[0]), hy = f2bf(p[1]), hz = f2bf(p[2]);
    float fx = bf2f(hx), fy = bf2f(hy), fz = bf2f(hz);
    float qq = fmaf(fx, fx, fmaf(fy, fy, fz * fz));
    unsigned short hh = f2bf(qq);
    unsigned short hl = f2bf(qq - bf2f(hh));
    bf16x8 a;
    a[0] = (short)f2bf(-2.0f * fx);      // exact: coords already bf16
    a[1] = (short)f2bf(-2.0f * fy);
    a[2] = (short)f2bf(-2.0f * fz);
    a[3] = (short)0x3F80;
    a[4] = (short)0x3F80;
    a[5] = (short)hh;
    a[6] = (short)hl;
    a[7] = 0;
    return a;
}

// ---------------------------------------------------------------------------
// Kernel 1: fused min+sum. Block = (dir, b, qg): 128 queries, all 8192 refs
// via 4 LDS-staged slices (packed on the fly from raw fp32). Scan per slice:
// R15 SW pipeline (issue tile t's 2 ds_read+2 MFMA, then fold tile t-1 into
// 4 independent min3 chains). After slices: sqrt, 32-lane sum, block sum,
// one partial per block (no atomics, no zero-init of out needed here).
// D layout (m74/m101): col = lane&31, row = (r&3)+8*(r>>2)+4*(lane>>5).
// ---------------------------------------------------------------------------
__global__ __launch_bounds__(THREADS) void min_sum_kernel(
    const float* __restrict__ gts, const float* __restrict__ preds,
    float* __restrict__ partial) {
    __shared__ uint4 sref[RPS];            // 32 KB
    __shared__ float wsum[4];

    int tid  = threadIdx.x;
    int blk  = blockIdx.x;
    int dir  = blk >> 8;                   // 0..1
    int b    = (blk >> 6) & 3;
    int qg   = blk & 63;

    int wid  = tid >> 6;
    int lane = tid & 63;
    int l31  = lane & 31;

    // dir0: queries=preds, refs=gts; dir1: swapped.
    const float* rbase = (dir ? preds : gts) + (size_t)b * NPTS * 3;
    const float* qsrc  = (dir ? gts : preds)
                       + ((size_t)b * NPTS + (size_t)qg * QPB
                          + (size_t)wid * QPW) * 3;

    // Persistent B fragment: lane l31 = query col l31; lanes 32-63 zero.
    bf16x8 bq = {0, 0, 0, 0, 0, 0, 0, 0};
    if (lane < 32) bq = make_qfrag(qsrc + 3 * l31);

    f32x16 zeroc;
    #pragma unroll
    for (int r = 0; r < 16; ++r) zeroc[r] = 0.0f;

    float c0 = 3.0e38f, c1 = 3.0e38f, c2 = 3.0e38f, c3 = 3.0e38f;

    for (int s = 0; s < SLICES; ++s) {
        // Stage slice s, packing raw fp32 -> bf16 frags on the fly.
        __syncthreads();                   // prior scan done before overwrite
        const float* rsrc = rbase + (size_t)s * RPS * 3;
        #pragma unroll
        for (int i = 0; i < RPS / THREADS; ++i) {
            int p = i * THREADS + tid;
            sref[p] = make_rfrag(rsrc[3 * p], rsrc[3 * p + 1], rsrc[3 * p + 2]);
        }
        __syncthreads();

        const bf16x8* sp = (const bf16x8*)sref;
        // Prologue: tile 0 in flight.
        f32x16 p0 = __builtin_amdgcn_mfma_f32_32x32x16_bf16(sp[l31], bq, zeroc, 0, 0, 0);
        f32x16 p1 = __builtin_amdgcn_mfma_f32_32x32x16_bf16(sp[32 + l31], bq, zeroc, 0, 0, 0);

        #pragma unroll 2
        for (int t = 1; t < RPS / 64; ++t) {
            bf16x8 n0 = sp[t * 64 + l31];
            bf16x8 n1 = sp[t * 64 + 32 + l31];
            f32x16 d0 = __builtin_amdgcn_mfma_f32_32x32x16_bf16(n0, bq, zeroc, 0, 0, 0);
            f32x16 d1 = __builtin_amdgcn_mfma_f32_32x32x16_bf16(n1, bq, zeroc, 0, 0, 0);
            #pragma unroll
            for (int r = 0; r < 16; r += 4) {
                c0 = fminf(fminf(p0[r],     p0[r + 1]), c0);   // v_min3_f32
                c1 = fminf(fminf(p0[r + 2], p0[r + 3]), c1);
                c2 = fminf(fminf(p1[r],     p1[r + 1]), c2);
                c3 = fminf(fminf(p1[r + 2], p1[r + 3]), c3);
            }
            p0 = d0;
            p1 = d1;
        }
        #pragma unroll
        for (int r = 0; r < 16; r += 4) {
            c0 = fminf(fminf(p0[r],     p0[r + 1]), c0);
            c1 = fminf(fminf(p0[r + 2], p0[r + 3]), c1);
            c2 = fminf(fminf(p1[r],     p1[r + 1]), c2);
            c3 = fminf(fminf(p1[r + 2], p1[r + 3]), c3);
        }
    }

    // Combine chains; wave halves hold complementary ref-rows.
    float m = fminf(fminf(c0, c1), fminf(c2, c3));
    m = fminf(m, __shfl_xor(m, 32, 64));
    float d = sqrtf(fmaxf(m, 0.0f));

    // Sum this wave's 32 query distances (upper half duplicates lower).
    float sum = d;
    sum += __shfl_down(sum, 16, 64);
    sum += __shfl_down(sum, 8, 64);
    sum += __shfl_down(sum, 4, 64);
    sum += __shfl_down(sum, 2, 64);
    sum += __shfl_down(sum, 1, 64);

    if (lane == 0) wsum[wid] = sum;
    __syncthreads();
    if (tid == 0)
        partial[blk] = wsum[0] + wsum[1] + wsum[2] + wsum[3];
}

// ---------------------------------------------------------------------------
// Kernel 2: reduce 512 partials -> out[4]. One block; wave w owns batch b=w
// (partial idx t: dir = t>>8, b = (t>>6)&3 == wave id for t<256).
// ---------------------------------------------------------------------------
__global__ __launch_bounds__(THREADS) void final_kernel(
    const float* __restrict__ partial, float* __restrict__ out) {
    int t = threadIdx.x;                   // 0..255
    float s = partial[t] + partial[t + 256];   // dir0 + dir1
    #pragma unroll
    for (int off = 32; off > 0; off >>= 1)
        s += __shfl_down(s, off, 64);
    if ((t & 63) == 0)
        out[t >> 6] = s;                   // direct store, no zero-init needed
}

extern "C" void kernel_launch(void* const* d_in, const int* in_sizes, int n_in,
                              void* d_out, int out_size, void* d_ws, size_t ws_size,
                              hipStream_t stream) {
    const float* gts   = (const float*)d_in[0];
    const float* preds = (const float*)d_in[1];
    float* out = (float*)d_out;
    float* partial = (float*)d_ws;         // 2 KB

    min_sum_kernel<<<NBLK, THREADS, 0, stream>>>(gts, preds, partial);
    final_kernel<<<1, THREADS, 0, stream>>>(partial, out);
}

// Round 17
// 82.866 us; speedup vs baseline: 1.0452x; 1.0452x over previous
//
#include <hip/hip_runtime.h>
#include <math.h>

// Problem constants: gts/preds [4, 8192, 3] fp32; out [4] fp32.
#define BB 4
#define NPTS 8192
#define THREADS 256
#define NQ_TOTAL (2 * BB * NPTS)       // 65536 (dir,b,q) query slots
#define SLICES 4                       // ref-dim split; 32 KB LDS per block
#define RPS (NPTS / SLICES)            // 2048 refs per slice
#define QPW 64                         // queries per wave (TWO B fragments)
#define QPB_MIN (4 * QPW)              // 256 queries per block (4 waves)
#define QGROUPS (NPTS / QPB_MIN)       // 32 query groups per (dir,b)
#define NBLK_MIN (SLICES * 2 * BB * QGROUPS)   // 1024 blocks

typedef __attribute__((ext_vector_type(8)))  short bf16x8;   // MFMA A/B frag
typedef __attribute__((ext_vector_type(16))) float f32x16;   // MFMA C/D frag

// ws layout:
//   refpack: NQ_TOTAL uint4  bf16 [x,y,z,rr_hi,rr_lo,1,1,0]       1 MiB
//   qpack:   NQ_TOTAL uint4  bf16 [-2x,-2y,-2z,1,1,qq_hi,qq_lo,0] 1 MiB
//   minpart: SLICES * NQ_TOTAL float                              1 MiB
// MFMA dot = -2 q.r + rr + qq = |q-r|^2 on bf16-rounded points.
// Role-swapped (R13): A = refs (rows, LDS), B = queries (cols, persistent).
// R17 = R15's SW pipeline + R14's dual-B: per iter 2 ds_read_b128 feed 4
// MFMAs (LDS bytes/pair halved), folds interleaved between the MFMA pairs
// so only <=4 result frags are live (~100 VGPR, 4 waves/SIMD kept).

__device__ __forceinline__ unsigned short f2bf(float f) {   // RNE f32->bf16
    unsigned u = __float_as_uint(f);
    u += 0x7FFF + ((u >> 16) & 1);
    return (unsigned short)(u >> 16);
}
__device__ __forceinline__ float bf2f(unsigned short h) {
    return __uint_as_float(((unsigned)h) << 16);
}

// ---------------------------------------------------------------------------
// Kernel 1: round coords to bf16, build ref- and query-side fragments.
// rr/qq computed in fp32 FROM THE ROUNDED coords, fed as 2-term bf16 splits.
// ---------------------------------------------------------------------------
__global__ __launch_bounds__(THREADS) void pack_kernel(
    const float* __restrict__ gts, const float* __restrict__ preds,
    uint4* __restrict__ refpack, uint4* __restrict__ qpack,
    float* __restrict__ out) {
    int idx = blockIdx.x * THREADS + threadIdx.x;
    if (idx < BB) out[idx] = 0.0f;
    if (idx >= NQ_TOTAL) return;
    int set  = idx / (BB * NPTS);          // 0 = gts, 1 = preds
    int pidx = idx - set * (BB * NPTS);
    const float* src = set ? preds : gts;
    unsigned short hx = f2bf(src[pidx * 3 + 0]);
    unsigned short hy = f2bf(src[pidx * 3 + 1]);
    unsigned short hz = f2bf(src[pidx * 3 + 2]);
    float fx = bf2f(hx), fy = bf2f(hy), fz = bf2f(hz);
    float rr = fmaf(fx, fx, fmaf(fy, fy, fz * fz));
    unsigned short hrr = f2bf(rr);
    unsigned short hlo = f2bf(rr - bf2f(hrr));
    const unsigned short ONE = 0x3F80;      // 1.0 bf16

    uint4 rv;                               // ref slots: [x,y,z,rrhi,rrlo,1,1,0]
    rv.x = (unsigned)hx  | ((unsigned)hy  << 16);
    rv.y = (unsigned)hz  | ((unsigned)hrr << 16);
    rv.z = (unsigned)hlo | ((unsigned)ONE << 16);
    rv.w = (unsigned)ONE;
    refpack[idx] = rv;

    unsigned short nx = f2bf(-2.0f * fx);   // exact (coords already bf16)
    unsigned short ny = f2bf(-2.0f * fy);
    unsigned short nz = f2bf(-2.0f * fz);
    uint4 qv;                               // query slots: [-2x,-2y,-2z,1,1,qqhi,qqlo,0]
    qv.x = (unsigned)nx  | ((unsigned)ny  << 16);
    qv.y = (unsigned)nz  | ((unsigned)ONE << 16);
    qv.z = (unsigned)ONE | ((unsigned)hrr << 16);
    qv.w = (unsigned)hlo;
    qpack[idx] = qv;
}

// ---------------------------------------------------------------------------
// Kernel 2: MFMA min kernel: role-swap + dual-B + interleaved SW pipeline.
// Steady state per iter: issue mfma(a1_prev,bq0/bq1); load tile t; fold
// d00/d01 (16 min3); issue mfma(a0_t,bq0/bq1); fold d10/d11 (16 min3).
// Every fold has 2 MFMAs in flight ahead of it; <=4 live result frags.
// Tail: 2 fminf + 2 shfl_xor(32) + 2 coalesced 32-lane stores.
// D layout (m74/m101): col = lane&31, row = (r&3)+8*(r>>2)+4*(lane>>5).
// ---------------------------------------------------------------------------
__global__ __launch_bounds__(THREADS) void min_kernel(
    const uint4* __restrict__ refpack, const uint4* __restrict__ qpack,
    float* __restrict__ minpart) {
    __shared__ uint4 sref[RPS];            // 32 KB

    int tid   = threadIdx.x;
    int blk   = blockIdx.x;
    int slice = blk >> 8;                  // / (2*BB*QGROUPS) = /256
    int rem   = blk & 255;
    int dir   = rem >> 7;
    int b     = (rem >> 5) & 3;
    int qg    = rem & 31;                  // query group of 256
    int qset  = dir ^ 1;                   // dir0: queries=preds(set1), refs=gts
    int rset  = dir;

    // Stage the ref slice: 2048 uint4, 8 coalesced rounds of 256 lanes.
    const uint4* rgl = refpack + (size_t)(rset * BB + b) * NPTS
                     + (size_t)slice * RPS;
    #pragma unroll
    for (int i = 0; i < RPS / THREADS; ++i)
        sref[i * THREADS + tid] = rgl[i * THREADS + tid];
    __syncthreads();

    int wid  = tid >> 6;
    int lane = tid & 63;
    int l31  = lane & 31;

    // Two B fragments: lane l31 = query cols l31 / l31+32; lanes 32-63 zero.
    size_t qoff = (size_t)(qset * BB + b) * NPTS + (size_t)qg * QPB_MIN
                + (size_t)wid * QPW;
    bf16x8 bq0 = {0, 0, 0, 0, 0, 0, 0, 0};
    bf16x8 bq1 = {0, 0, 0, 0, 0, 0, 0, 0};
    if (lane < 32) {
        bq0 = ((const bf16x8*)qpack)[qoff + l31];
        bq1 = ((const bf16x8*)qpack)[qoff + 32 + l31];
    }

    f32x16 zeroc;
    #pragma unroll
    for (int r = 0; r < 16; ++r) zeroc[r] = 0.0f;

    // 4 chains: cA* fold bq0's distances, cB* fold bq1's.
    float cA0 = 3.0e38f, cA1 = 3.0e38f, cB0 = 3.0e38f, cB1 = 3.0e38f;

    const bf16x8* sp = (const bf16x8*)sref;

    // Prologue: tile 0 loaded; first MFMA pair in flight.
    bf16x8 a0 = sp[l31];
    bf16x8 a1 = sp[32 + l31];
    f32x16 d00 = __builtin_amdgcn_mfma_f32_32x32x16_bf16(a0, bq0, zeroc, 0, 0, 0);
    f32x16 d01 = __builtin_amdgcn_mfma_f32_32x32x16_bf16(a0, bq1, zeroc, 0, 0, 0);

    #pragma unroll 2
    for (int t = 1; t < RPS / 64; ++t) {
        // Second MFMA pair of tile t-1 (uses a1 of previous tile).
        f32x16 d10 = __builtin_amdgcn_mfma_f32_32x32x16_bf16(a1, bq0, zeroc, 0, 0, 0);
        f32x16 d11 = __builtin_amdgcn_mfma_f32_32x32x16_bf16(a1, bq1, zeroc, 0, 0, 0);
        // Load tile t (independent).
        a0 = sp[t * 64 + l31];
        a1 = sp[t * 64 + 32 + l31];
        // Fold first pair of tile t-1 (2 MFMAs in flight behind it).
        #pragma unroll
        for (int r = 0; r < 16; r += 2) {
            cA0 = fminf(fminf(d00[r], d00[r + 1]), cA0);   // v_min3_f32
            cB0 = fminf(fminf(d01[r], d01[r + 1]), cB0);
        }
        // First MFMA pair of tile t.
        d00 = __builtin_amdgcn_mfma_f32_32x32x16_bf16(a0, bq0, zeroc, 0, 0, 0);
        d01 = __builtin_amdgcn_mfma_f32_32x32x16_bf16(a0, bq1, zeroc, 0, 0, 0);
        // Fold second pair of tile t-1.
        #pragma unroll
        for (int r = 0; r < 16; r += 2) {
            cA1 = fminf(fminf(d10[r], d10[r + 1]), cA1);
            cB1 = fminf(fminf(d11[r], d11[r + 1]), cB1);
        }
    }
    // Epilogue: last tile's second pair + both folds.
    {
        f32x16 d10 = __builtin_amdgcn_mfma_f32_32x32x16_bf16(a1, bq0, zeroc, 0, 0, 0);
        f32x16 d11 = __builtin_amdgcn_mfma_f32_32x32x16_bf16(a1, bq1, zeroc, 0, 0, 0);
        #pragma unroll
        for (int r = 0; r < 16; r += 2) {
            cA0 = fminf(fminf(d00[r], d00[r + 1]), cA0);
            cB0 = fminf(fminf(d01[r], d01[r + 1]), cB0);
        }
        #pragma unroll
        for (int r = 0; r < 16; r += 2) {
            cA1 = fminf(fminf(d10[r], d10[r + 1]), cA1);
            cB1 = fminf(fminf(d11[r], d11[r + 1]), cB1);
        }
    }

    // Combine chains; wave halves hold complementary ref-rows.
    float q0 = fminf(cA0, cA1);
    float q1 = fminf(cB0, cB1);
    q0 = fminf(q0, __shfl_xor(q0, 32, 64));
    q1 = fminf(q1, __shfl_xor(q1, 32, 64));

    float* mp = minpart + (size_t)slice * NQ_TOTAL
              + (size_t)(dir * BB + b) * NPTS + (size_t)qg * QPB_MIN
              + (size_t)wid * QPW;
    if (lane < 32) {
        mp[l31]      = q0;
        mp[l31 + 32] = q1;
    }
}

// ---------------------------------------------------------------------------
// Kernel 3: merge slices, sqrt, block-reduce, atomicAdd into out[b].
// ---------------------------------------------------------------------------
__global__ __launch_bounds__(THREADS) void merge_kernel(
    const float* __restrict__ minpart, float* __restrict__ out) {
    int q = blockIdx.x * THREADS + threadIdx.x;    // 0 .. NQ_TOTAL-1
    float m = minpart[q];
    #pragma unroll
    for (int s = 1; s < SLICES; ++s)
        m = fminf(m, minpart[(size_t)s * NQ_TOTAL + q]);
    float d = sqrtf(fmaxf(m, 0.0f));
    int b = (q >> 13) & 3;                         // uniform within a block

    float sum = d;
    #pragma unroll
    for (int off = 32; off > 0; off >>= 1)
        sum += __shfl_down(sum, off, 64);

    __shared__ float wsum[THREADS / 64];
    int lane = threadIdx.x & 63;
    int wid  = threadIdx.x >> 6;
    if (lane == 0) wsum[wid] = sum;
    __syncthreads();
    if (threadIdx.x == 0)
        atomicAdd(out + b, wsum[0] + wsum[1] + wsum[2] + wsum[3]);
}

extern "C" void kernel_launch(void* const* d_in, const int* in_sizes, int n_in,
                              void* d_out, int out_size, void* d_ws, size_t ws_size,
                              hipStream_t stream) {
    const float* gts   = (const float*)d_in[0];
    const float* preds = (const float*)d_in[1];
    float* out = (float*)d_out;

    char* ws = (char*)d_ws;
    uint4* refpack = (uint4*)ws;                                   // 1 MiB
    uint4* qpack   = (uint4*)(ws + (size_t)NQ_TOTAL * 16);         // 1 MiB
    float* minpart = (float*)(ws + (size_t)NQ_TOTAL * 32);         // 1 MiB

    pack_kernel<<<NQ_TOTAL / THREADS, THREADS, 0, stream>>>(
        gts, preds, refpack, qpack, out);

    min_kernel<<<NBLK_MIN, THREADS, 0, stream>>>(refpack, qpack, minpart);

    merge_kernel<<<NQ_TOTAL / THREADS, THREADS, 0, stream>>>(minpart, out);
}